// Round 4
// baseline (1390.350 us; speedup 1.0000x reference)
//
#include <hip/hip_runtime.h>
#include <math.h>

#define B 2
#define L 4096
#define D 1024
#define OD 3072
#define NORD 2
#define EMBD 33
#define FREQF 10.0f
#define NFFT 8192
#define FFT_THREADS 512
#define RPT (NFFT / FFT_THREADS) /* 16 */
#define PI_F 3.14159265358979323846f

// ---------------------------------------------------------------------------
// In-LDS radix-2 FFT, length 8192, 512 threads.
// fft_dif: natural input -> bit-reversed output, forward twiddles e^{-i...}
// fft_dit_inv: bit-reversed input -> natural order, inverse twiddles, no 1/N.
// Pointwise products happen in scrambled order; no bit-reversal pass exists.
// After fft_dit_inv, each thread's owned positions {tid + rr*512} were written
// by itself in the last stage, so same-thread reads need no trailing sync.
// ---------------------------------------------------------------------------
__device__ __forceinline__ void fft_dif(float2* z, int tid) {
  for (int half = NFFT >> 1; half >= 1; half >>= 1) {
    float nih = -PI_F / (float)half;
    __syncthreads();
#pragma unroll
    for (int r = 0; r < NFFT / 2 / FFT_THREADS; ++r) {
      int j = tid + r * FFT_THREADS;
      int t = j & (half - 1);
      int i0 = 2 * j - t;
      int i1 = i0 + half;
      float2 a = z[i0], b = z[i1];
      float dx = a.x - b.x, dy = a.y - b.y;
      float s, c;
      __sincosf(nih * (float)t, &s, &c);
      z[i0] = make_float2(a.x + b.x, a.y + b.y);
      z[i1] = make_float2(dx * c - dy * s, dx * s + dy * c);
    }
  }
  __syncthreads();
}

__device__ __forceinline__ void fft_dit_inv(float2* z, int tid) {
  for (int half = 1; half <= (NFFT >> 1); half <<= 1) {
    float pih = PI_F / (float)half;
    __syncthreads();
#pragma unroll
    for (int r = 0; r < NFFT / 2 / FFT_THREADS; ++r) {
      int j = tid + r * FFT_THREADS;
      int t = j & (half - 1);
      int i0 = 2 * j - t;
      int i1 = i0 + half;
      float s, c;
      __sincosf(pih * (float)t, &s, &c);
      float2 a = z[i0], b = z[i1];
      float bx = b.x * c - b.y * s;
      float by = b.x * s + b.y * c;
      z[i0] = make_float2(a.x + bx, a.y + by);
      z[i1] = make_float2(a.x - bx, a.y - by);
    }
  }
  // no trailing sync: callers only touch same-thread positions next.
}

// ---------------------------------------------------------------------------
// S[t,k] = sin(FREQ * (sum_j sin(t/(L-1) * j * FREQ) * w1[k,j] + b1[k]))
// ---------------------------------------------------------------------------
__global__ void s_kernel(const float* __restrict__ w1, const float* __restrict__ b1,
                         float* __restrict__ S) {
  int idx = blockIdx.x * blockDim.x + threadIdx.x;
  if (idx >= L * 64) return;
  int t = idx >> 6, k = idx & 63;
  float tn = (float)t * (1.0f / (float)(L - 1));
  float acc = b1[k];
#pragma unroll
  for (int j = 0; j < EMBD; ++j) {
    acc += sinf(tn * (float)j * FREQF) * w1[k * EMBD + j];
  }
  S[idx] = sinf(FREQF * acc);
}

// ---------------------------------------------------------------------------
// gemm_in: res_t[b, c, l] = sum_d u[b,l,d]*w_in[c,d] + b_in[c]
// C-tile 128 x L-tile 64, 256 threads, 8x4 micro-tile, K-step 16.
// ---------------------------------------------------------------------------
__global__ __launch_bounds__(256) void gemm_in_kernel(
    const float* __restrict__ u, const float* __restrict__ w_in,
    const float* __restrict__ b_in, float* __restrict__ res_t) {
  __shared__ float As[16][132];  // As[kk][ci] = w_in[c0+ci, k0+kk]
  __shared__ float Bs[16][68];   // Bs[kk][li] = u[b, l0+li, k0+kk]
  int b = blockIdx.z;
  int c0 = blockIdx.y * 128;
  int l0 = blockIdx.x * 64;
  int t = threadIdx.x;
  int tx = t & 15, ty = t >> 4;
  const float* ub = u + (size_t)b * L * D;

  float acc[8][4];
#pragma unroll
  for (int i = 0; i < 8; ++i)
#pragma unroll
    for (int j = 0; j < 4; ++j) acc[i][j] = 0.0f;

  for (int k0 = 0; k0 < D; k0 += 16) {
#pragma unroll
    for (int rep = 0; rep < 2; ++rep) {
      int v = t + rep * 256;
      int row = v >> 2;
      int kq = (v & 3) << 2;
      float4 a4 = *(const float4*)(w_in + (size_t)(c0 + row) * D + k0 + kq);
      As[kq + 0][row] = a4.x; As[kq + 1][row] = a4.y;
      As[kq + 2][row] = a4.z; As[kq + 3][row] = a4.w;
    }
    {
      int row = t >> 2;
      int kq = (t & 3) << 2;
      float4 b4 = *(const float4*)(ub + (size_t)(l0 + row) * D + k0 + kq);
      Bs[kq + 0][row] = b4.x; Bs[kq + 1][row] = b4.y;
      Bs[kq + 2][row] = b4.z; Bs[kq + 3][row] = b4.w;
    }
    __syncthreads();
#pragma unroll
    for (int kk = 0; kk < 16; ++kk) {
      float4 a0 = *(const float4*)&As[kk][ty * 8];
      float4 a1 = *(const float4*)&As[kk][ty * 8 + 4];
      float4 bv = *(const float4*)&Bs[kk][tx * 4];
      float a[8] = {a0.x, a0.y, a0.z, a0.w, a1.x, a1.y, a1.z, a1.w};
      float bb[4] = {bv.x, bv.y, bv.z, bv.w};
#pragma unroll
      for (int i = 0; i < 8; ++i)
#pragma unroll
        for (int j = 0; j < 4; ++j) acc[i][j] = fmaf(a[i], bb[j], acc[i][j]);
    }
    __syncthreads();
  }
#pragma unroll
  for (int i = 0; i < 8; ++i) {
    int c = c0 + ty * 8 + i;
    float bi = b_in[c];
    float4 o = make_float4(acc[i][0] + bi, acc[i][1] + bi, acc[i][2] + bi, acc[i][3] + bi);
    *(float4*)(res_t + ((size_t)(b * OD + c)) * L + l0 + tx * 4) = o;
  }
}

// ---------------------------------------------------------------------------
// build_filter: compute h[c][0..L-1] into z (zero-padded to NFFT), DIF-FFT,
// snapshot this thread's 16 scrambled spectrum points into H (VGPRs).
// h[t] = ((S[t,:] . w2[c,:]) + b2[c]) * exp(-exp(fd[c]) * t/(L-1)) + fb[c],
// all * (1/L)
// ---------------------------------------------------------------------------
__device__ __forceinline__ void build_filter(
    int c, const float* __restrict__ S, const float* __restrict__ w2,
    const float* __restrict__ b2, const float* __restrict__ filt_bias,
    const float* __restrict__ filt_decay, float2* z, int tid, float2 (&H)[RPT]) {
  float mu = __expf(filt_decay[c]);
  float fb = filt_bias[c];
  float bb = b2[c];
  const float* wr = w2 + (size_t)c * 64;
#pragma unroll
  for (int rr = 0; rr < RPT; ++rr) {
    int t = tid + (rr << 9);
    float val = 0.0f;
    if (t < L) {
      float acc = bb;
      const float4* S4 = (const float4*)(S + (size_t)t * 64);
#pragma unroll
      for (int kq = 0; kq < 16; ++kq) {
        float4 s4 = S4[kq];
        acc += s4.x * wr[kq * 4 + 0] + s4.y * wr[kq * 4 + 1] +
               s4.z * wr[kq * 4 + 2] + s4.w * wr[kq * 4 + 3];
      }
      float tn = (float)t * (1.0f / (float)(L - 1));
      val = (acc * __expf(-mu * tn) + fb) * (1.0f / (float)L);
    }
    z[t] = make_float2(val, 0.0f);
  }
  fft_dif(z, tid);  // leading syncs cover the writes above; trailing sync inside
#pragma unroll
  for (int rr = 0; rr < RPT; ++rr) H[rr] = z[tid + (rr << 9)];
  // next z overwrite is by the same thread at the same positions: no sync needed
}

__device__ __forceinline__ float conv3pt(const float* __restrict__ r, int t,
                                         float w0, float w1, float w2c, float cb) {
  float xm = (t > 0) ? r[t - 1] : 0.0f;
  float x0 = r[t];
  float xp = (t < L - 1) ? r[t + 1] : 0.0f;
  return w0 * xm + w1 * x0 + w2c * xp + cb;
}

// ---------------------------------------------------------------------------
// conv_fft: one block per channel d. Both batches packed as z = v0 + i*v1
// (y_b = irfft(V_b*H) are each real, so IFFT(Z*H) = y0 + i*y1).
// Filter spectra H0,H1 live in registers at this thread's scrambled positions.
// Depthwise conv3 and gates fused; nothing but res_t read / vfin written.
// ---------------------------------------------------------------------------
__global__ __launch_bounds__(FFT_THREADS) void conv_fft_kernel(
    const float* __restrict__ res_t, const float* __restrict__ conv_w,
    const float* __restrict__ conv_b, const float* __restrict__ S,
    const float* __restrict__ w2, const float* __restrict__ b2,
    const float* __restrict__ filt_bias, const float* __restrict__ filt_decay,
    float* __restrict__ vfin) {
  __shared__ float2 z[NFFT];
  int d = blockIdx.x;
  int tid = threadIdx.x;

  float2 H0[RPT], H1[RPT];
  build_filter(d,     S, w2, b2, filt_bias, filt_decay, z, tid, H0);
  build_filter(D + d, S, w2, b2, filt_bias, filt_decay, z, tid, H1);

  // ---- build packed v = conv3(res_t[b, 2D+d, :]) for b=0 (re), b=1 (im) ----
  {
    int c = 2 * D + d;
    const float* r0 = res_t + ((size_t)(0 * OD + c)) * L;
    const float* r1 = res_t + ((size_t)(1 * OD + c)) * L;
    float w0 = conv_w[c * 3 + 0], w1 = conv_w[c * 3 + 1], w2c = conv_w[c * 3 + 2];
    float cb = conv_b[c];
#pragma unroll
    for (int rr = 0; rr < RPT; ++rr) {
      int t = tid + (rr << 9);
      float2 val = make_float2(0.0f, 0.0f);
      if (t < L) {
        val.x = conv3pt(r0, t, w0, w1, w2c, cb);
        val.y = conv3pt(r1, t, w0, w1, w2c, cb);
      }
      z[t] = val;
    }
  }

  // ---- order 0: FFT, *H0, IFFT, gate with conv3(x0), repack ----
  fft_dif(z, tid);
#pragma unroll
  for (int rr = 0; rr < RPT; ++rr) {
    int p = tid + (rr << 9);
    float2 a = z[p];
    float2 f = H0[rr];
    z[p] = make_float2(a.x * f.x - a.y * f.y, a.x * f.y + a.y * f.x);
  }
  fft_dit_inv(z, tid);
  {
    int c = d;  // n = 0
    const float* r0 = res_t + ((size_t)(0 * OD + c)) * L;
    const float* r1 = res_t + ((size_t)(1 * OD + c)) * L;
    float w0 = conv_w[c * 3 + 0], w1 = conv_w[c * 3 + 1], w2c = conv_w[c * 3 + 2];
    float cb = conv_b[c];
#pragma unroll
    for (int rr = 0; rr < RPT; ++rr) {
      int t = tid + (rr << 9);
      float2 val = make_float2(0.0f, 0.0f);
      if (t < L) {
        float2 y = z[t];  // written by this thread in last IFFT stage
        val.x = y.x * (1.0f / (float)NFFT) * conv3pt(r0, t, w0, w1, w2c, cb);
        val.y = y.y * (1.0f / (float)NFFT) * conv3pt(r1, t, w0, w1, w2c, cb);
      }
      z[t] = val;
    }
  }

  // ---- order 1: FFT, *H1, IFFT, gate with conv3(x1), write out ----
  fft_dif(z, tid);
#pragma unroll
  for (int rr = 0; rr < RPT; ++rr) {
    int p = tid + (rr << 9);
    float2 a = z[p];
    float2 f = H1[rr];
    z[p] = make_float2(a.x * f.x - a.y * f.y, a.x * f.y + a.y * f.x);
  }
  fft_dit_inv(z, tid);
  {
    int c = D + d;  // n = 1
    const float* r0 = res_t + ((size_t)(0 * OD + c)) * L;
    const float* r1 = res_t + ((size_t)(1 * OD + c)) * L;
    float w0 = conv_w[c * 3 + 0], w1 = conv_w[c * 3 + 1], w2c = conv_w[c * 3 + 2];
    float cb = conv_b[c];
    float* vo0 = vfin + ((size_t)(0 * D + d)) * L;
    float* vo1 = vfin + ((size_t)(1 * D + d)) * L;
#pragma unroll
    for (int rr = 0; rr < L / FFT_THREADS; ++rr) {
      int t = tid + (rr << 9);
      float2 y = z[t];  // same-thread positions
      vo0[t] = y.x * (1.0f / (float)NFFT) * conv3pt(r0, t, w0, w1, w2c, cb);
      vo1[t] = y.y * (1.0f / (float)NFFT) * conv3pt(r1, t, w0, w1, w2c, cb);
    }
  }
}

// ---------------------------------------------------------------------------
// gemm_out: out[b,l,j] = sum_d vfin[b,d,l] * w_out[j,d] + b_out[j]
// J-tile 128 x L-tile 64, 256 threads, 8x4 micro-tile, K-step 16.
// ---------------------------------------------------------------------------
__global__ __launch_bounds__(256) void gemm_out_kernel(
    const float* __restrict__ vfin, const float* __restrict__ w_out,
    const float* __restrict__ b_out, float* __restrict__ out) {
  __shared__ float Ws[16][132];  // Ws[kk][ji] = w_out[j0+ji, d0+kk]
  __shared__ float As[16][68];   // As[kk][li] = vfin[b, d0+kk, l0+li]
  int b = blockIdx.z;
  int j0 = blockIdx.y * 128;
  int l0 = blockIdx.x * 64;
  int t = threadIdx.x;
  int tx = t & 15, ty = t >> 4;
  const float* A = vfin + (size_t)b * D * L;

  float acc[8][4];
#pragma unroll
  for (int i = 0; i < 8; ++i)
#pragma unroll
    for (int j = 0; j < 4; ++j) acc[i][j] = 0.0f;

  for (int k0 = 0; k0 < D; k0 += 16) {
#pragma unroll
    for (int rep = 0; rep < 2; ++rep) {
      int v = t + rep * 256;
      int row = v >> 2;
      int kq = (v & 3) << 2;
      float4 a4 = *(const float4*)(w_out + (size_t)(j0 + row) * D + k0 + kq);
      Ws[kq + 0][row] = a4.x; Ws[kq + 1][row] = a4.y;
      Ws[kq + 2][row] = a4.z; Ws[kq + 3][row] = a4.w;
    }
    {
      int kk = t >> 4;
      int q = t & 15;
      float4 a4 = *(const float4*)(A + (size_t)(k0 + kk) * L + l0 + q * 4);
      *(float4*)&As[kk][q * 4] = a4;
    }
    __syncthreads();
#pragma unroll
    for (int kk = 0; kk < 16; ++kk) {
      float4 a0 = *(const float4*)&Ws[kk][ty * 8];
      float4 a1 = *(const float4*)&Ws[kk][ty * 8 + 4];
      float4 bv = *(const float4*)&As[kk][tx * 4];
      float a[8] = {a0.x, a0.y, a0.z, a0.w, a1.x, a1.y, a1.z, a1.w};
      float bb[4] = {bv.x, bv.y, bv.z, bv.w};
#pragma unroll
      for (int i = 0; i < 8; ++i)
#pragma unroll
        for (int j = 0; j < 4; ++j) acc[i][j] = fmaf(a[i], bb[j], acc[i][j]);
    }
    __syncthreads();
  }
  float bo[8];
#pragma unroll
  for (int i = 0; i < 8; ++i) bo[i] = b_out[j0 + ty * 8 + i];
#pragma unroll
  for (int jj = 0; jj < 4; ++jj) {
    int l = l0 + tx * 4 + jj;
    float* o = out + ((size_t)(b * L + l)) * D + j0 + ty * 8;
    float4 o0 = make_float4(acc[0][jj] + bo[0], acc[1][jj] + bo[1],
                            acc[2][jj] + bo[2], acc[3][jj] + bo[3]);
    float4 o1 = make_float4(acc[4][jj] + bo[4], acc[5][jj] + bo[5],
                            acc[6][jj] + bo[6], acc[7][jj] + bo[7]);
    *(float4*)o = o0;
    *((float4*)o + 1) = o1;
  }
}

// ---------------------------------------------------------------------------
extern "C" void kernel_launch(void* const* d_in, const int* in_sizes, int n_in,
                              void* d_out, int out_size, void* d_ws, size_t ws_size,
                              hipStream_t stream) {
  const float* u = (const float*)d_in[0];
  const float* w_in = (const float*)d_in[1];
  const float* b_in = (const float*)d_in[2];
  const float* conv_w = (const float*)d_in[3];
  const float* conv_b = (const float*)d_in[4];
  const float* w1 = (const float*)d_in[5];
  const float* b1 = (const float*)d_in[6];
  const float* w2 = (const float*)d_in[7];
  const float* b2 = (const float*)d_in[8];
  const float* filt_bias = (const float*)d_in[9];
  const float* filt_decay = (const float*)d_in[10];
  const float* w_out = (const float*)d_in[11];
  const float* b_out = (const float*)d_in[12];
  float* out = (float*)d_out;

  // workspace layout (bytes), total 129 MiB:
  //   res_t: [0, 96 MiB)        B*OD*L f32
  //   vfin:  [96, 128 MiB)      B*D*L f32
  //   S:     [128, 129 MiB)     L*64 f32
  char* ws = (char*)d_ws;
  float* res_t = (float*)(ws);
  float* vfin = (float*)(ws + (size_t)96 * 1024 * 1024);
  float* S = (float*)(ws + (size_t)128 * 1024 * 1024);

  s_kernel<<<(L * 64 + 255) / 256, 256, 0, stream>>>(w1, b1, S);
  gemm_in_kernel<<<dim3(L / 64, OD / 128, B), 256, 0, stream>>>(u, w_in, b_in, res_t);
  conv_fft_kernel<<<D, FFT_THREADS, 0, stream>>>(res_t, conv_w, conv_b, S, w2, b2,
                                                 filt_bias, filt_decay, vfin);
  gemm_out_kernel<<<dim3(L / 64, D / 128, B), 256, 0, stream>>>(vfin, w_out, b_out, out);
}

// Round 15
// 797.419 us; speedup vs baseline: 1.7436x; 1.7436x over previous
//
#include <hip/hip_runtime.h>
#include <math.h>

#define B 2
#define L 4096
#define D 1024
#define OD 3072
#define NORD 2
#define EMBD 33
#define FREQF 10.0f
#define NFFT 8192
#define FFT_THREADS 512
#define RPT (NFFT / FFT_THREADS) /* 16 */
#define PI_F 3.14159265358979323846f
#define MIB 1048576ULL

typedef short bfrag8 __attribute__((ext_vector_type(8)));
typedef float floatx4 __attribute__((ext_vector_type(4)));

// ---------------------------------------------------------------------------
// fp32 -> (bf16 hi, bf16 lo) split: x ~= hi + lo, each RNE-rounded.
// ---------------------------------------------------------------------------
__device__ __forceinline__ void split1(float x, ushort& h, ushort& l) {
  unsigned ux = __float_as_uint(x);
  unsigned hb = (ux + 0x7fffu + ((ux >> 16) & 1u)) & 0xffff0000u;
  h = (ushort)(hb >> 16);
  float r = x - __uint_as_float(hb);
  unsigned ur = __float_as_uint(r);
  l = (ushort)((ur + 0x7fffu + ((ur >> 16) & 1u)) >> 16);
}

__global__ void cvt_split_kernel(const float* __restrict__ src, ushort* __restrict__ hi,
                                 ushort* __restrict__ lo, int n4) {
  int i = blockIdx.x * blockDim.x + threadIdx.x;
  int stride = gridDim.x * blockDim.x;
  for (; i < n4; i += stride) {
    float4 x = ((const float4*)src)[i];
    ushort4 h, l;
    split1(x.x, h.x, l.x);
    split1(x.y, h.y, l.y);
    split1(x.z, h.z, l.z);
    split1(x.w, h.w, l.w);
    ((ushort4*)hi)[i] = h;
    ((ushort4*)lo)[i] = l;
  }
}

__device__ __forceinline__ bfrag8 ldfrag(const ushort* p) {
  union { bfrag8 v; ushort4 u[2]; } f;
  f.u[0] = *(const ushort4*)(p);
  f.u[1] = *(const ushort4*)(p + 4);
  return f.v;
}

// ---------------------------------------------------------------------------
// In-LDS radix-2 FFT, length 8192, 512 threads (unchanged from r2, verified).
// ---------------------------------------------------------------------------
__device__ __forceinline__ void fft_dif(float2* z, int tid) {
  for (int half = NFFT >> 1; half >= 1; half >>= 1) {
    float nih = -PI_F / (float)half;
    __syncthreads();
#pragma unroll
    for (int r = 0; r < NFFT / 2 / FFT_THREADS; ++r) {
      int j = tid + r * FFT_THREADS;
      int t = j & (half - 1);
      int i0 = 2 * j - t;
      int i1 = i0 + half;
      float2 a = z[i0], b = z[i1];
      float dx = a.x - b.x, dy = a.y - b.y;
      float s, c;
      __sincosf(nih * (float)t, &s, &c);
      z[i0] = make_float2(a.x + b.x, a.y + b.y);
      z[i1] = make_float2(dx * c - dy * s, dx * s + dy * c);
    }
  }
  __syncthreads();
}

__device__ __forceinline__ void fft_dit_inv(float2* z, int tid) {
  for (int half = 1; half <= (NFFT >> 1); half <<= 1) {
    float pih = PI_F / (float)half;
    __syncthreads();
#pragma unroll
    for (int r = 0; r < NFFT / 2 / FFT_THREADS; ++r) {
      int j = tid + r * FFT_THREADS;
      int t = j & (half - 1);
      int i0 = 2 * j - t;
      int i1 = i0 + half;
      float s, c;
      __sincosf(pih * (float)t, &s, &c);
      float2 a = z[i0], b = z[i1];
      float bx = b.x * c - b.y * s;
      float by = b.x * s + b.y * c;
      z[i0] = make_float2(a.x + bx, a.y + by);
      z[i1] = make_float2(a.x - bx, a.y - by);
    }
  }
}

// ---------------------------------------------------------------------------
// S[t,k] = sin(FREQ * (sum_j sin(t/(L-1) * j * FREQ) * w1[k,j] + b1[k]))
// ---------------------------------------------------------------------------
__global__ void s_kernel(const float* __restrict__ w1, const float* __restrict__ b1,
                         float* __restrict__ S) {
  int idx = blockIdx.x * blockDim.x + threadIdx.x;
  if (idx >= L * 64) return;
  int t = idx >> 6, k = idx & 63;
  float tn = (float)t * (1.0f / (float)(L - 1));
  float acc = b1[k];
#pragma unroll
  for (int j = 0; j < EMBD; ++j) {
    acc += sinf(tn * (float)j * FREQF) * w1[k * EMBD + j];
  }
  S[idx] = sinf(FREQF * acc);
}

// ---------------------------------------------------------------------------
// gemm_in (MFMA split-bf16): res_t[b,c,l] = sum_d u[b,l,d]*w_in[c,d] + b_in[c]
// 128x128 tile, 4 waves (2x2 of 64x64), BK=32, LDS rows padded to 36 ushort.
// Staging: 128 rows x 32 cols = 1024 ushort4 slots = 256 threads x 4 reps.
// (r14 fix: was 2 reps -> rows 64-127 uninitialized -> NaN.)
// ---------------------------------------------------------------------------
__global__ __launch_bounds__(256) void gemm_in_mfma(
    const ushort* __restrict__ uh, const ushort* __restrict__ ul,
    const ushort* __restrict__ wh, const ushort* __restrict__ wl,
    const float* __restrict__ b_in, float* __restrict__ res_t) {
  __shared__ ushort Ah[128][36], Al[128][36], Bh[128][36], Bl[128][36];
  int b = blockIdx.z;
  int c0 = blockIdx.y * 128;
  int l0 = blockIdx.x * 128;
  int t = threadIdx.x;
  int wid = t >> 6, lane = t & 63;
  int wr = wid >> 1, wc = wid & 1;
  int ra = lane & 15, ko = (lane >> 4) * 8;
  size_t ub = ((size_t)b * L + l0) * D;

  floatx4 zero = {0.0f, 0.0f, 0.0f, 0.0f};
  floatx4 acc[4][4];
#pragma unroll
  for (int i = 0; i < 4; ++i)
#pragma unroll
    for (int j = 0; j < 4; ++j) acc[i][j] = zero;

  for (int k0 = 0; k0 < D; k0 += 32) {
#pragma unroll
    for (int i = 0; i < 4; ++i) {
      int f = t + i * 256;          // [0,1024): covers all 128 rows x 8 ushort4
      int r = f >> 3, c4 = (f & 7) * 4;
      *(ushort4*)&Ah[r][c4] = *(const ushort4*)(wh + (size_t)(c0 + r) * D + k0 + c4);
      *(ushort4*)&Al[r][c4] = *(const ushort4*)(wl + (size_t)(c0 + r) * D + k0 + c4);
      *(ushort4*)&Bh[r][c4] = *(const ushort4*)(uh + ub + (size_t)r * D + k0 + c4);
      *(ushort4*)&Bl[r][c4] = *(const ushort4*)(ul + ub + (size_t)r * D + k0 + c4);
    }
    __syncthreads();
    bfrag8 ah[4], al[4];
#pragma unroll
    for (int mf = 0; mf < 4; ++mf) {
      int r = wr * 64 + mf * 16 + ra;
      ah[mf] = ldfrag(&Ah[r][ko]);
      al[mf] = ldfrag(&Al[r][ko]);
    }
#pragma unroll
    for (int nf = 0; nf < 4; ++nf) {
      int r = wc * 64 + nf * 16 + ra;
      bfrag8 bh = ldfrag(&Bh[r][ko]);
      bfrag8 bl = ldfrag(&Bl[r][ko]);
#pragma unroll
      for (int mf = 0; mf < 4; ++mf) {
        acc[mf][nf] = __builtin_amdgcn_mfma_f32_16x16x32_bf16(ah[mf], bl, acc[mf][nf], 0, 0, 0);
        acc[mf][nf] = __builtin_amdgcn_mfma_f32_16x16x32_bf16(al[mf], bh, acc[mf][nf], 0, 0, 0);
        acc[mf][nf] = __builtin_amdgcn_mfma_f32_16x16x32_bf16(ah[mf], bh, acc[mf][nf], 0, 0, 0);
      }
    }
    __syncthreads();
  }

#pragma unroll
  for (int mf = 0; mf < 4; ++mf) {
    int cb = c0 + wr * 64 + mf * 16 + ((lane >> 4) << 2);
    float bi[4];
#pragma unroll
    for (int r = 0; r < 4; ++r) bi[r] = b_in[cb + r];
#pragma unroll
    for (int nf = 0; nf < 4; ++nf) {
      int lcol = l0 + wc * 64 + nf * 16 + (lane & 15);
#pragma unroll
      for (int r = 0; r < 4; ++r) {
        res_t[((size_t)b * OD + cb + r) * L + lcol] = acc[mf][nf][r] + bi[r];
      }
    }
  }
}

// ---------------------------------------------------------------------------
// gemm_out (MFMA split-bf16): out[b,l,j] = sum_d vfin[b,d,l]*w_out[j,d]+b_out[j]
// rows = l (vfin^T, transposed+converted in staging), cols = j (w_out hi/lo).
// B-tile staging: 4 reps (r14 fix, same as gemm_in).
// ---------------------------------------------------------------------------
__global__ __launch_bounds__(256) void gemm_out_mfma(
    const float* __restrict__ vfin, const ushort* __restrict__ wh,
    const ushort* __restrict__ wl, const float* __restrict__ b_out,
    float* __restrict__ out) {
  __shared__ ushort Ah[128][36], Al[128][36], Bh[128][36], Bl[128][36];
  int b = blockIdx.z;
  int l0 = blockIdx.y * 128;
  int j0 = blockIdx.x * 128;
  int t = threadIdx.x;
  int wid = t >> 6, lane = t & 63;
  int wr = wid >> 1, wc = wid & 1;
  int ra = lane & 15, ko = (lane >> 4) * 8;
  int rl = t & 127;   // l-row this thread stages
  int ks = t >> 7;    // which 16-wide k segment (0/1)

  floatx4 zero = {0.0f, 0.0f, 0.0f, 0.0f};
  floatx4 acc[4][4];
#pragma unroll
  for (int i = 0; i < 4; ++i)
#pragma unroll
    for (int j = 0; j < 4; ++j) acc[i][j] = zero;

  for (int k0 = 0; k0 < D; k0 += 32) {
    // A-tile: transpose vfin[d][l] -> Ah/Al[l][d] with fp32->hi/lo conversion.
    // Coverage: 256 threads x (rl, ks) x 16 kk = 128 rows x 32 cols exactly.
    ushort hh[16], ll[16];
#pragma unroll
    for (int kk = 0; kk < 16; ++kk) {
      float x = vfin[(size_t)(b * D + k0 + ks * 16 + kk) * L + l0 + rl];
      split1(x, hh[kk], ll[kk]);
    }
#pragma unroll
    for (int g = 0; g < 4; ++g) {
      ushort4 hv = make_ushort4(hh[g * 4 + 0], hh[g * 4 + 1], hh[g * 4 + 2], hh[g * 4 + 3]);
      ushort4 lv = make_ushort4(ll[g * 4 + 0], ll[g * 4 + 1], ll[g * 4 + 2], ll[g * 4 + 3]);
      *(ushort4*)&Ah[rl][ks * 16 + g * 4] = hv;
      *(ushort4*)&Al[rl][ks * 16 + g * 4] = lv;
    }
    // B-tile: w_out rows j, K-contiguous (prepassed bf16 hi/lo), 4 reps.
#pragma unroll
    for (int i = 0; i < 4; ++i) {
      int f = t + i * 256;
      int r = f >> 3, c4 = (f & 7) * 4;
      *(ushort4*)&Bh[r][c4] = *(const ushort4*)(wh + (size_t)(j0 + r) * D + k0 + c4);
      *(ushort4*)&Bl[r][c4] = *(const ushort4*)(wl + (size_t)(j0 + r) * D + k0 + c4);
    }
    __syncthreads();
    bfrag8 ah[4], al[4];
#pragma unroll
    for (int mf = 0; mf < 4; ++mf) {
      int r = wr * 64 + mf * 16 + ra;
      ah[mf] = ldfrag(&Ah[r][ko]);
      al[mf] = ldfrag(&Al[r][ko]);
    }
#pragma unroll
    for (int nf = 0; nf < 4; ++nf) {
      int r = wc * 64 + nf * 16 + ra;
      bfrag8 bh = ldfrag(&Bh[r][ko]);
      bfrag8 bl = ldfrag(&Bl[r][ko]);
#pragma unroll
      for (int mf = 0; mf < 4; ++mf) {
        acc[mf][nf] = __builtin_amdgcn_mfma_f32_16x16x32_bf16(ah[mf], bl, acc[mf][nf], 0, 0, 0);
        acc[mf][nf] = __builtin_amdgcn_mfma_f32_16x16x32_bf16(al[mf], bh, acc[mf][nf], 0, 0, 0);
        acc[mf][nf] = __builtin_amdgcn_mfma_f32_16x16x32_bf16(ah[mf], bh, acc[mf][nf], 0, 0, 0);
      }
    }
    __syncthreads();
  }

#pragma unroll
  for (int nf = 0; nf < 4; ++nf) {
    int j = j0 + wc * 64 + nf * 16 + (lane & 15);
    float bo = b_out[j];
#pragma unroll
    for (int mf = 0; mf < 4; ++mf) {
      int lb = l0 + wr * 64 + mf * 16 + ((lane >> 4) << 2);
#pragma unroll
      for (int r = 0; r < 4; ++r) {
        out[((size_t)b * L + lb + r) * D + j] = acc[mf][nf][r] + bo;
      }
    }
  }
}

// ---------------------------------------------------------------------------
// build_filter + conv_fft (unchanged from round 2, verified passing).
// ---------------------------------------------------------------------------
__device__ __forceinline__ void build_filter(
    int c, const float* __restrict__ S, const float* __restrict__ w2,
    const float* __restrict__ b2, const float* __restrict__ filt_bias,
    const float* __restrict__ filt_decay, float2* z, int tid, float2 (&H)[RPT]) {
  float mu = __expf(filt_decay[c]);
  float fb = filt_bias[c];
  float bb = b2[c];
  const float* wr = w2 + (size_t)c * 64;
#pragma unroll
  for (int rr = 0; rr < RPT; ++rr) {
    int t = tid + (rr << 9);
    float val = 0.0f;
    if (t < L) {
      float acc = bb;
      const float4* S4 = (const float4*)(S + (size_t)t * 64);
#pragma unroll
      for (int kq = 0; kq < 16; ++kq) {
        float4 s4 = S4[kq];
        acc += s4.x * wr[kq * 4 + 0] + s4.y * wr[kq * 4 + 1] +
               s4.z * wr[kq * 4 + 2] + s4.w * wr[kq * 4 + 3];
      }
      float tn = (float)t * (1.0f / (float)(L - 1));
      val = (acc * __expf(-mu * tn) + fb) * (1.0f / (float)L);
    }
    z[t] = make_float2(val, 0.0f);
  }
  fft_dif(z, tid);
#pragma unroll
  for (int rr = 0; rr < RPT; ++rr) H[rr] = z[tid + (rr << 9)];
}

__device__ __forceinline__ float conv3pt(const float* __restrict__ r, int t,
                                         float w0, float w1, float w2c, float cb) {
  float xm = (t > 0) ? r[t - 1] : 0.0f;
  float x0 = r[t];
  float xp = (t < L - 1) ? r[t + 1] : 0.0f;
  return w0 * xm + w1 * x0 + w2c * xp + cb;
}

__global__ __launch_bounds__(FFT_THREADS) void conv_fft_kernel(
    const float* __restrict__ res_t, const float* __restrict__ conv_w,
    const float* __restrict__ conv_b, const float* __restrict__ S,
    const float* __restrict__ w2, const float* __restrict__ b2,
    const float* __restrict__ filt_bias, const float* __restrict__ filt_decay,
    float* __restrict__ vfin) {
  __shared__ float2 z[NFFT];
  int d = blockIdx.x;
  int tid = threadIdx.x;

  float2 H0[RPT], H1[RPT];
  build_filter(d, S, w2, b2, filt_bias, filt_decay, z, tid, H0);
  build_filter(D + d, S, w2, b2, filt_bias, filt_decay, z, tid, H1);

  {
    int c = 2 * D + d;
    const float* r0 = res_t + ((size_t)(0 * OD + c)) * L;
    const float* r1 = res_t + ((size_t)(1 * OD + c)) * L;
    float w0 = conv_w[c * 3 + 0], w1 = conv_w[c * 3 + 1], w2c = conv_w[c * 3 + 2];
    float cb = conv_b[c];
#pragma unroll
    for (int rr = 0; rr < RPT; ++rr) {
      int t = tid + (rr << 9);
      float2 val = make_float2(0.0f, 0.0f);
      if (t < L) {
        val.x = conv3pt(r0, t, w0, w1, w2c, cb);
        val.y = conv3pt(r1, t, w0, w1, w2c, cb);
      }
      z[t] = val;
    }
  }

  fft_dif(z, tid);
#pragma unroll
  for (int rr = 0; rr < RPT; ++rr) {
    int p = tid + (rr << 9);
    float2 a = z[p];
    float2 f = H0[rr];
    z[p] = make_float2(a.x * f.x - a.y * f.y, a.x * f.y + a.y * f.x);
  }
  fft_dit_inv(z, tid);
  {
    int c = d;
    const float* r0 = res_t + ((size_t)(0 * OD + c)) * L;
    const float* r1 = res_t + ((size_t)(1 * OD + c)) * L;
    float w0 = conv_w[c * 3 + 0], w1 = conv_w[c * 3 + 1], w2c = conv_w[c * 3 + 2];
    float cb = conv_b[c];
#pragma unroll
    for (int rr = 0; rr < RPT; ++rr) {
      int t = tid + (rr << 9);
      float2 val = make_float2(0.0f, 0.0f);
      if (t < L) {
        float2 y = z[t];
        val.x = y.x * (1.0f / (float)NFFT) * conv3pt(r0, t, w0, w1, w2c, cb);
        val.y = y.y * (1.0f / (float)NFFT) * conv3pt(r1, t, w0, w1, w2c, cb);
      }
      z[t] = val;
    }
  }

  fft_dif(z, tid);
#pragma unroll
  for (int rr = 0; rr < RPT; ++rr) {
    int p = tid + (rr << 9);
    float2 a = z[p];
    float2 f = H1[rr];
    z[p] = make_float2(a.x * f.x - a.y * f.y, a.x * f.y + a.y * f.x);
  }
  fft_dit_inv(z, tid);
  {
    int c = D + d;
    const float* r0 = res_t + ((size_t)(0 * OD + c)) * L;
    const float* r1 = res_t + ((size_t)(1 * OD + c)) * L;
    float w0 = conv_w[c * 3 + 0], w1 = conv_w[c * 3 + 1], w2c = conv_w[c * 3 + 2];
    float cb = conv_b[c];
    float* vo0 = vfin + ((size_t)(0 * D + d)) * L;
    float* vo1 = vfin + ((size_t)(1 * D + d)) * L;
#pragma unroll
    for (int rr = 0; rr < L / FFT_THREADS; ++rr) {
      int t = tid + (rr << 9);
      float2 y = z[t];
      vo0[t] = y.x * (1.0f / (float)NFFT) * conv3pt(r0, t, w0, w1, w2c, cb);
      vo1[t] = y.y * (1.0f / (float)NFFT) * conv3pt(r1, t, w0, w1, w2c, cb);
    }
  }
}

// ---------------------------------------------------------------------------
extern "C" void kernel_launch(void* const* d_in, const int* in_sizes, int n_in,
                              void* d_out, int out_size, void* d_ws, size_t ws_size,
                              hipStream_t stream) {
  const float* u = (const float*)d_in[0];
  const float* w_in = (const float*)d_in[1];
  const float* b_in = (const float*)d_in[2];
  const float* conv_w = (const float*)d_in[3];
  const float* conv_b = (const float*)d_in[4];
  const float* w1 = (const float*)d_in[5];
  const float* b1 = (const float*)d_in[6];
  const float* w2 = (const float*)d_in[7];
  const float* b2 = (const float*)d_in[8];
  const float* filt_bias = (const float*)d_in[9];
  const float* filt_decay = (const float*)d_in[10];
  const float* w_out = (const float*)d_in[11];
  const float* b_out = (const float*)d_in[12];
  float* out = (float*)d_out;

  // workspace layout (MiB), total 145:
  //   res_t    [0,96)    B*OD*L f32
  //   u_hi     [96,112)  \ aliases vfin [96,128): u_* dead after gemm_in,
  //   u_lo     [112,128) / conv_fft then writes vfin there.
  //   S        [128,129)
  //   w_in_hi  [129,135)  w_in_lo [135,141)
  //   w_out_hi [141,143)  w_out_lo [143,145)
  char* ws = (char*)d_ws;
  float* res_t = (float*)(ws);
  float* vfin = (float*)(ws + 96 * MIB);
  ushort* u_hi = (ushort*)(ws + 96 * MIB);
  ushort* u_lo = (ushort*)(ws + 112 * MIB);
  float* S = (float*)(ws + 128 * MIB);
  ushort* w_in_hi = (ushort*)(ws + 129 * MIB);
  ushort* w_in_lo = (ushort*)(ws + 135 * MIB);
  ushort* w_out_hi = (ushort*)(ws + 141 * MIB);
  ushort* w_out_lo = (ushort*)(ws + 143 * MIB);

  cvt_split_kernel<<<2048, 256, 0, stream>>>(u, u_hi, u_lo, B * L * D / 4);
  cvt_split_kernel<<<1024, 256, 0, stream>>>(w_in, w_in_hi, w_in_lo, OD * D / 4);
  cvt_split_kernel<<<512, 256, 0, stream>>>(w_out, w_out_hi, w_out_lo, D * D / 4);
  s_kernel<<<(L * 64 + 255) / 256, 256, 0, stream>>>(w1, b1, S);
  gemm_in_mfma<<<dim3(L / 128, OD / 128, B), 256, 0, stream>>>(u_hi, u_lo, w_in_hi,
                                                               w_in_lo, b_in, res_t);
  conv_fft_kernel<<<D, FFT_THREADS, 0, stream>>>(res_t, conv_w, conv_b, S, w2, b2,
                                                 filt_bias, filt_decay, vfin);
  gemm_out_mfma<<<dim3(D / 128, L / 128, B), 256, 0, stream>>>(vfin, w_out_hi, w_out_lo,
                                                               b_out, out);
}